// Round 1
// baseline (132.713 us; speedup 1.0000x reference)
//
#include <hip/hip_runtime.h>
#include <hip/hip_bf16.h>

typedef __attribute__((ext_vector_type(4))) float f32x4;
typedef __attribute__((ext_vector_type(8))) __bf16 bf16x8;
typedef __attribute__((ext_vector_type(8))) unsigned short u16x8;

constexpr int BROWS = 4096;   // proteins (output rows)
constexpr int NCOLS = 8192;   // functions (output cols)
constexpr int DK    = 1024;   // inner dim
constexpr int BM = 128, BN = 128, BK = 32;
constexpr int LDK = BK + 8;   // +16B row pad: 80B stride keeps 16B align, <=2-way LDS conflicts
constexpr int NCB = NCOLS / BN;  // 64 column blocks

__device__ static inline unsigned short f2bf(float f) {
  unsigned int u = __builtin_bit_cast(unsigned int, f);
  u += 0x7FFFu + ((u >> 16) & 1u);   // round-to-nearest-even
  return (unsigned short)(u >> 16);
}

// f32 -> bf16 conversion; optionally folds the 1/exp(temperature) scale into P.
__global__ void convert_kernel(const float* __restrict__ src,
                               unsigned short* __restrict__ dst,
                               int n4, int applyScale,
                               const float* __restrict__ temp) {
  float scale = applyScale ? expf(-temp[0]) : 1.0f;
  int i = blockIdx.x * blockDim.x + threadIdx.x;
  if (i >= n4) return;
  float4 v = reinterpret_cast<const float4*>(src)[i];
  ushort4 o;
  o.x = f2bf(v.x * scale);
  o.y = f2bf(v.y * scale);
  o.z = f2bf(v.z * scale);
  o.w = f2bf(v.w * scale);
  reinterpret_cast<ushort4*>(dst)[i] = o;
}

// Fused bf16 MFMA GEMM tile + per-(row, colblock) online-softmax partials.
// partials[row*NCB + cb] = {rowmax, sum exp(x-rowmax), sum mask*x, count mask}
__global__ __launch_bounds__(256, 2)
void main_kernel(const unsigned short* __restrict__ Pb,
                 const unsigned short* __restrict__ Fb,
                 const int* __restrict__ mask,
                 f32x4* __restrict__ partials) {
  __shared__ __align__(16) unsigned short As[BM * LDK];
  __shared__ __align__(16) unsigned short Bs[BN * LDK];
  __shared__ float redM[2][BM];
  __shared__ float redS[2][BM];
  __shared__ float redP[2][BM];
  __shared__ float redC[2][BM];

  const int t    = threadIdx.x;
  const int lane = t & 63;
  const int w    = t >> 6;       // wave id 0..3
  const int wr   = w >> 1;       // wave row (0..1), 64 output rows each
  const int wc   = w & 1;        // wave col (0..1), 64 output cols each
  const int l15  = lane & 15;
  const int l4   = lane >> 4;

  const int brow = blockIdx.y * BM;
  const int bcol = blockIdx.x * BN;

  f32x4 acc[4][4] = {};

  // staging: 512 chunks of 8 bf16 per operand tile, 2 per thread
  const int c0row = t >> 2,          c0k = (t & 3) * 8;
  const int c1row = (t + 256) >> 2,  c1k = ((t + 256) & 3) * 8;

  for (int k0 = 0; k0 < DK; k0 += BK) {
    u16x8 a0 = *reinterpret_cast<const u16x8*>(&Pb[(size_t)(brow + c0row) * DK + k0 + c0k]);
    u16x8 a1 = *reinterpret_cast<const u16x8*>(&Pb[(size_t)(brow + c1row) * DK + k0 + c1k]);
    u16x8 b0 = *reinterpret_cast<const u16x8*>(&Fb[(size_t)(bcol + c0row) * DK + k0 + c0k]);
    u16x8 b1 = *reinterpret_cast<const u16x8*>(&Fb[(size_t)(bcol + c1row) * DK + k0 + c1k]);
    *reinterpret_cast<u16x8*>(&As[c0row * LDK + c0k]) = a0;
    *reinterpret_cast<u16x8*>(&As[c1row * LDK + c1k]) = a1;
    *reinterpret_cast<u16x8*>(&Bs[c0row * LDK + c0k]) = b0;
    *reinterpret_cast<u16x8*>(&Bs[c1row * LDK + c1k]) = b1;
    __syncthreads();

    bf16x8 af[4], bfr[4];
#pragma unroll
    for (int i = 0; i < 4; ++i) {
      af[i]  = __builtin_bit_cast(bf16x8,
                 *reinterpret_cast<const u16x8*>(&As[(wr * 64 + i * 16 + l15) * LDK + l4 * 8]));
      bfr[i] = __builtin_bit_cast(bf16x8,
                 *reinterpret_cast<const u16x8*>(&Bs[(wc * 64 + i * 16 + l15) * LDK + l4 * 8]));
    }
#pragma unroll
    for (int i = 0; i < 4; ++i)
#pragma unroll
      for (int j = 0; j < 4; ++j)
        acc[i][j] = __builtin_amdgcn_mfma_f32_16x16x32_bf16(af[i], bfr[j], acc[i][j], 0, 0, 0);
    __syncthreads();
  }

  // Epilogue: C/D layout col=lane&15, row=(lane>>4)*4+reg (m89-verified).
  // For each of this lane's 16 (i,r) rows: reduce over j (4 cols) then 16 lanes.
#pragma unroll
  for (int i = 0; i < 4; ++i) {
#pragma unroll
    for (int r = 0; r < 4; ++r) {
      float v0 = acc[i][0][r], v1 = acc[i][1][r], v2 = acc[i][2][r], v3 = acc[i][3][r];
      float mx = fmaxf(fmaxf(v0, v1), fmaxf(v2, v3));
#pragma unroll
      for (int s = 1; s < 16; s <<= 1) mx = fmaxf(mx, __shfl_xor(mx, s, 64));
      float se = __expf(v0 - mx) + __expf(v1 - mx) + __expf(v2 - mx) + __expf(v3 - mx);

      const int lrow = wr * 64 + i * 16 + l4 * 4 + r;
      const int* mrow = mask + (size_t)(brow + lrow) * NCOLS + bcol + wc * 64 + l15;
      float ps = 0.f, pc = 0.f;
      if (mrow[0]  == 1) { ps += v0; pc += 1.f; }
      if (mrow[16] == 1) { ps += v1; pc += 1.f; }
      if (mrow[32] == 1) { ps += v2; pc += 1.f; }
      if (mrow[48] == 1) { ps += v3; pc += 1.f; }
#pragma unroll
      for (int s = 1; s < 16; s <<= 1) {
        se += __shfl_xor(se, s, 64);
        ps += __shfl_xor(ps, s, 64);
        pc += __shfl_xor(pc, s, 64);
      }
      if (l15 == 0) {
        redM[wc][lrow] = mx;
        redS[wc][lrow] = se;
        redP[wc][lrow] = ps;
        redC[wc][lrow] = pc;
      }
    }
  }
  __syncthreads();

  if (t < BM) {
    float m0 = redM[0][t], m1 = redM[1][t];
    float m  = fmaxf(m0, m1);
    float s  = redS[0][t] * __expf(m0 - m) + redS[1][t] * __expf(m1 - m);
    float ps = redP[0][t] + redP[1][t];
    float pc = redC[0][t] + redC[1][t];
    f32x4 out4;
    out4.x = m; out4.y = s; out4.z = ps; out4.w = pc;
    partials[(size_t)(brow + t) * NCB + blockIdx.x] = out4;
  }
}

// One wave per row: combine the 64 column-block partials -> per-row contribution.
__global__ void row_reduce_kernel(const f32x4* __restrict__ partials,
                                  float* __restrict__ rowContrib,
                                  float* __restrict__ rowCnt) {
  const int row  = blockIdx.x * 4 + (threadIdx.x >> 6);
  const int lane = threadIdx.x & 63;
  f32x4 p = partials[(size_t)row * NCB + lane];   // NCB == 64 == wave size
  float m = p.x;
#pragma unroll
  for (int s = 1; s < 64; s <<= 1) m = fmaxf(m, __shfl_xor(m, s, 64));
  float se = p.y * __expf(p.x - m);
  float ps = p.z, pc = p.w;
#pragma unroll
  for (int s = 1; s < 64; s <<= 1) {
    se += __shfl_xor(se, s, 64);
    ps += __shfl_xor(ps, s, 64);
    pc += __shfl_xor(pc, s, 64);
  }
  if (lane == 0) {
    float lse = m + logf(se);
    rowContrib[row] = pc * lse - ps;
    rowCnt[row]     = pc;
  }
}

__global__ void final_kernel(const float* __restrict__ rowContrib,
                             const float* __restrict__ rowCnt,
                             float* __restrict__ out) {
  __shared__ double sC[256];
  __shared__ double sN[256];
  double c = 0.0, n = 0.0;
  for (int i = threadIdx.x; i < BROWS; i += 256) {
    c += (double)rowContrib[i];
    n += (double)rowCnt[i];
  }
  sC[threadIdx.x] = c;
  sN[threadIdx.x] = n;
  __syncthreads();
  for (int s = 128; s > 0; s >>= 1) {
    if ((int)threadIdx.x < s) {
      sC[threadIdx.x] += sC[threadIdx.x + s];
      sN[threadIdx.x] += sN[threadIdx.x + s];
    }
    __syncthreads();
  }
  if (threadIdx.x == 0) out[0] = (sN[0] > 0.0) ? (float)(sC[0] / sN[0]) : 0.0f;
}

extern "C" void kernel_launch(void* const* d_in, const int* in_sizes, int n_in,
                              void* d_out, int out_size, void* d_ws, size_t ws_size,
                              hipStream_t stream) {
  const float* P    = (const float*)d_in[0];
  const float* F    = (const float*)d_in[1];
  const int*   mask = (const int*)d_in[2];
  const float* temp = (const float*)d_in[3];
  float* out = (float*)d_out;

  char* ws = (char*)d_ws;
  unsigned short* Pb = (unsigned short*)ws;                       // 8 MB
  unsigned short* Fb = (unsigned short*)(ws + (size_t)BROWS * DK * 2);  // 16 MB
  f32x4* partials    = (f32x4*)(ws + (size_t)(BROWS + NCOLS) * DK * 2); // 4 MB
  float* rowContrib  = (float*)((char*)partials + (size_t)BROWS * NCB * sizeof(f32x4));
  float* rowCnt      = rowContrib + BROWS;

  const int nP4 = BROWS * DK / 4;
  const int nF4 = NCOLS * DK / 4;
  hipLaunchKernelGGL(convert_kernel, dim3(nP4 / 256), dim3(256), 0, stream, P, Pb, nP4, 1, temp);
  hipLaunchKernelGGL(convert_kernel, dim3(nF4 / 256), dim3(256), 0, stream, F, Fb, nF4, 0, temp);
  hipLaunchKernelGGL(main_kernel, dim3(NCB, BROWS / BM), dim3(256), 0, stream, Pb, Fb, mask, partials);
  hipLaunchKernelGGL(row_reduce_kernel, dim3(BROWS / 4), dim3(256), 0, stream, partials, rowContrib, rowCnt);
  hipLaunchKernelGGL(final_kernel, dim3(1), dim3(256), 0, stream, rowContrib, rowCnt, out);
}

// Round 2
// 126.413 us; speedup vs baseline: 1.0498x; 1.0498x over previous
//
#include <hip/hip_runtime.h>
#include <hip/hip_bf16.h>

typedef __attribute__((ext_vector_type(4))) float f32x4;
typedef __attribute__((ext_vector_type(8))) __bf16 bf16x8;
typedef __attribute__((ext_vector_type(8))) unsigned short u16x8;

constexpr int BROWS = 4096;   // proteins (output rows)
constexpr int NCOLS = 8192;   // functions (output cols)
constexpr int DK    = 1024;   // inner dim
constexpr int BM = 128, BN = 128, BK = 32;
constexpr int NCB = NCOLS / BN;  // 64 column blocks

__device__ static inline unsigned short f2bf(float f) {
  unsigned int u = __builtin_bit_cast(unsigned int, f);
  u += 0x7FFFu + ((u >> 16) & 1u);   // round-to-nearest-even
  return (unsigned short)(u >> 16);
}

// async global->LDS, 16B per lane, wave-uniform LDS base (HW: base + lane*16)
__device__ static inline void gload16(const void* g, void* l) {
  __builtin_amdgcn_global_load_lds(
      (const __attribute__((address_space(1))) void*)g,
      (__attribute__((address_space(3))) void*)l, 16, 0, 0);
}

// f32 -> bf16 conversion; optionally folds the 1/exp(temperature) scale into P.
__global__ void convert_kernel(const float* __restrict__ src,
                               unsigned short* __restrict__ dst,
                               int n4, int applyScale,
                               const float* __restrict__ temp) {
  float scale = applyScale ? expf(-temp[0]) : 1.0f;
  int i = blockIdx.x * blockDim.x + threadIdx.x;
  if (i >= n4) return;
  float4 v = reinterpret_cast<const float4*>(src)[i];
  ushort4 o;
  o.x = f2bf(v.x * scale);
  o.y = f2bf(v.y * scale);
  o.z = f2bf(v.z * scale);
  o.w = f2bf(v.w * scale);
  reinterpret_cast<ushort4*>(dst)[i] = o;
}

// Fused bf16 MFMA GEMM tile (m97 structure: global_load_lds width=16, linear LDS)
// + per-(row, colblock) online-softmax partials.
// partials[row*NCB + cb] = {rowmax, sum exp(x-rowmax), sum mask*x, count mask}
__global__ __launch_bounds__(256, 2)
void main_kernel(const unsigned short* __restrict__ Pb,
                 const unsigned short* __restrict__ Fb,
                 const int* __restrict__ mask,
                 f32x4* __restrict__ partials) {
  __shared__ __align__(16) unsigned short As[BM * BK];  // linear [row][k], 64B rows
  __shared__ __align__(16) unsigned short Bs[BN * BK];
  __shared__ float redM[2][BM];
  __shared__ float redS[2][BM];
  __shared__ float redP[2][BM];
  __shared__ float redC[2][BM];

  const int t    = threadIdx.x;
  const int lane = t & 63;
  const int w    = t >> 6;       // wave id 0..3
  const int wr   = w >> 1;       // wave row (0..1), 64 output rows each
  const int wc   = w & 1;        // wave col (0..1), 64 output cols each
  const int l15  = lane & 15;
  const int l4   = lane >> 4;

  const int brow = blockIdx.y * BM;
  const int bcol = blockIdx.x * BN;

  f32x4 acc[4][4] = {};

  // staging: 8 chunks of 1024B per operand; wave w owns chunks {2w, 2w+1} of each.
  // chunk c: rows [16c, 16c+16), lane l -> row 16c + (l>>2), k-elem (l&3)*8
  const int cA = w * 2;
  const int rowInC = lane >> 2;
  const int kInC   = (lane & 3) * 8;

  const unsigned short* Pg = Pb + (size_t)brow * DK;
  const unsigned short* Fg = Fb + (size_t)bcol * DK;

  for (int k0 = 0; k0 < DK; k0 += BK) {
    if (k0) __syncthreads();   // previous tile fully consumed before overwrite
    gload16(&Pg[(size_t)(cA * 16 + rowInC) * DK + k0 + kInC],       &As[cA * 512]);
    gload16(&Pg[(size_t)((cA + 1) * 16 + rowInC) * DK + k0 + kInC], &As[(cA + 1) * 512]);
    gload16(&Fg[(size_t)(cA * 16 + rowInC) * DK + k0 + kInC],       &Bs[cA * 512]);
    gload16(&Fg[(size_t)((cA + 1) * 16 + rowInC) * DK + k0 + kInC], &Bs[(cA + 1) * 512]);
    __syncthreads();           // compiler drains vmcnt(0) before barrier

    bf16x8 af[4], bfr[4];
#pragma unroll
    for (int i = 0; i < 4; ++i) {
      af[i]  = __builtin_bit_cast(bf16x8,
                 *reinterpret_cast<const u16x8*>(&As[(wr * 64 + i * 16 + l15) * BK + l4 * 8]));
      bfr[i] = __builtin_bit_cast(bf16x8,
                 *reinterpret_cast<const u16x8*>(&Bs[(wc * 64 + i * 16 + l15) * BK + l4 * 8]));
    }
#pragma unroll
    for (int i = 0; i < 4; ++i)
#pragma unroll
      for (int j = 0; j < 4; ++j)
        acc[i][j] = __builtin_amdgcn_mfma_f32_16x16x32_bf16(af[i], bfr[j], acc[i][j], 0, 0, 0);
  }

  // Epilogue: C/D layout col=lane&15, row=(lane>>4)*4+reg (m89-verified).
#pragma unroll
  for (int i = 0; i < 4; ++i) {
#pragma unroll
    for (int r = 0; r < 4; ++r) {
      float v0 = acc[i][0][r], v1 = acc[i][1][r], v2 = acc[i][2][r], v3 = acc[i][3][r];
      float mx = fmaxf(fmaxf(v0, v1), fmaxf(v2, v3));
#pragma unroll
      for (int s = 1; s < 16; s <<= 1) mx = fmaxf(mx, __shfl_xor(mx, s, 64));
      float se = __expf(v0 - mx) + __expf(v1 - mx) + __expf(v2 - mx) + __expf(v3 - mx);

      const int lrow = wr * 64 + i * 16 + l4 * 4 + r;
      const int* mrow = mask + (size_t)(brow + lrow) * NCOLS + bcol + wc * 64 + l15;
      float ps = 0.f, pc = 0.f;
      if (mrow[0]  == 1) { ps += v0; pc += 1.f; }
      if (mrow[16] == 1) { ps += v1; pc += 1.f; }
      if (mrow[32] == 1) { ps += v2; pc += 1.f; }
      if (mrow[48] == 1) { ps += v3; pc += 1.f; }
#pragma unroll
      for (int s = 1; s < 16; s <<= 1) {
        se += __shfl_xor(se, s, 64);
        ps += __shfl_xor(ps, s, 64);
        pc += __shfl_xor(pc, s, 64);
      }
      if (l15 == 0) {
        redM[wc][lrow] = mx;
        redS[wc][lrow] = se;
        redP[wc][lrow] = ps;
        redC[wc][lrow] = pc;
      }
    }
  }
  __syncthreads();

  if (t < BM) {
    float m0 = redM[0][t], m1 = redM[1][t];
    float m  = fmaxf(m0, m1);
    float s  = redS[0][t] * __expf(m0 - m) + redS[1][t] * __expf(m1 - m);
    float ps = redP[0][t] + redP[1][t];
    float pc = redC[0][t] + redC[1][t];
    f32x4 out4;
    out4.x = m; out4.y = s; out4.z = ps; out4.w = pc;
    partials[(size_t)(brow + t) * NCB + blockIdx.x] = out4;
  }
}

// One wave per row: combine the 64 column-block partials -> per-row contribution.
__global__ void row_reduce_kernel(const f32x4* __restrict__ partials,
                                  float* __restrict__ rowContrib,
                                  float* __restrict__ rowCnt) {
  const int row  = blockIdx.x * 4 + (threadIdx.x >> 6);
  const int lane = threadIdx.x & 63;
  f32x4 p = partials[(size_t)row * NCB + lane];   // NCB == 64 == wave size
  float m = p.x;
#pragma unroll
  for (int s = 1; s < 64; s <<= 1) m = fmaxf(m, __shfl_xor(m, s, 64));
  float se = p.y * __expf(p.x - m);
  float ps = p.z, pc = p.w;
#pragma unroll
  for (int s = 1; s < 64; s <<= 1) {
    se += __shfl_xor(se, s, 64);
    ps += __shfl_xor(ps, s, 64);
    pc += __shfl_xor(pc, s, 64);
  }
  if (lane == 0) {
    float lse = m + logf(se);
    rowContrib[row] = pc * lse - ps;
    rowCnt[row]     = pc;
  }
}

__global__ void final_kernel(const float* __restrict__ rowContrib,
                             const float* __restrict__ rowCnt,
                             float* __restrict__ out) {
  __shared__ double sC[256];
  __shared__ double sN[256];
  double c = 0.0, n = 0.0;
  for (int i = threadIdx.x; i < BROWS; i += 256) {
    c += (double)rowContrib[i];
    n += (double)rowCnt[i];
  }
  sC[threadIdx.x] = c;
  sN[threadIdx.x] = n;
  __syncthreads();
  for (int s = 128; s > 0; s >>= 1) {
    if ((int)threadIdx.x < s) {
      sC[threadIdx.x] += sC[threadIdx.x + s];
      sN[threadIdx.x] += sN[threadIdx.x + s];
    }
    __syncthreads();
  }
  if (threadIdx.x == 0) out[0] = (sN[0] > 0.0) ? (float)(sC[0] / sN[0]) : 0.0f;
}

extern "C" void kernel_launch(void* const* d_in, const int* in_sizes, int n_in,
                              void* d_out, int out_size, void* d_ws, size_t ws_size,
                              hipStream_t stream) {
  const float* P    = (const float*)d_in[0];
  const float* F    = (const float*)d_in[1];
  const int*   mask = (const int*)d_in[2];
  const float* temp = (const float*)d_in[3];
  float* out = (float*)d_out;

  char* ws = (char*)d_ws;
  unsigned short* Pb = (unsigned short*)ws;                       // 8 MB
  unsigned short* Fb = (unsigned short*)(ws + (size_t)BROWS * DK * 2);  // 16 MB
  f32x4* partials    = (f32x4*)(ws + (size_t)(BROWS + NCOLS) * DK * 2); // 4 MB
  float* rowContrib  = (float*)((char*)partials + (size_t)BROWS * NCB * sizeof(f32x4));
  float* rowCnt      = rowContrib + BROWS;

  const int nP4 = BROWS * DK / 4;
  const int nF4 = NCOLS * DK / 4;
  hipLaunchKernelGGL(convert_kernel, dim3(nP4 / 256), dim3(256), 0, stream, P, Pb, nP4, 1, temp);
  hipLaunchKernelGGL(convert_kernel, dim3(nF4 / 256), dim3(256), 0, stream, F, Fb, nF4, 0, temp);
  hipLaunchKernelGGL(main_kernel, dim3(NCB, BROWS / BM), dim3(256), 0, stream, Pb, Fb, mask, partials);
  hipLaunchKernelGGL(row_reduce_kernel, dim3(BROWS / 4), dim3(256), 0, stream, partials, rowContrib, rowCnt);
  hipLaunchKernelGGL(final_kernel, dim3(1), dim3(256), 0, stream, rowContrib, rowCnt, out);
}